// Round 1
// baseline (903.896 us; speedup 1.0000x reference)
//
#include <hip/hip_runtime.h>
#include <cstdint>
#include <cstddef>

// ---------------- problem constants ----------------
#define VOCAB 32000
#define EMB   256
#define HID   1024
#define NB    16      // batch
#define SS    512     // seq
#define MTOK  (NB*SS) // 8192 tokens
#define KDIM  1024    // NM1*EMB = HID
#define NCHUNK 500    // 32000 / 64 cols per wave-chunk
#define PSTRIDE 512   // padded chunk stride

typedef __bf16 bf16_t;
typedef bf16_t bf16x8 __attribute__((ext_vector_type(8)));
typedef float  f32x4  __attribute__((ext_vector_type(4)));

__device__ __forceinline__ unsigned short f32_to_bf16(float f) {
  union { float f; unsigned int u; } v; v.f = f;
  unsigned int u = v.u;
  unsigned int r = (u + 0x7FFFu + ((u >> 16) & 1u)) >> 16; // RNE
  return (unsigned short)r;
}

// global -> LDS direct copy, 16B per lane. LDS dest must be linear in lane order.
__device__ __forceinline__ void gload_lds16(const void* gsrc, void* ldst) {
  __builtin_amdgcn_global_load_lds(
      (__attribute__((address_space(1))) void*)gsrc,
      (__attribute__((address_space(3))) void*)ldst,
      16, 0, 0);
}

// ---------------- transpose + f32->bf16 convert: in[R][C] -> out[C][R] ----------------
__global__ void k_transpose_bf16(const float* __restrict__ in,
                                 unsigned short* __restrict__ out,
                                 int R, int C) {
  __shared__ float tile[32][33];
  int bc = blockIdx.x * 32, br = blockIdx.y * 32;
  int tx = threadIdx.x & 31, ty = threadIdx.x >> 5; // 256 threads, ty in 0..7
#pragma unroll
  for (int i = 0; i < 32; i += 8)
    tile[ty + i][tx] = in[(size_t)(br + ty + i) * C + (bc + tx)];
  __syncthreads();
#pragma unroll
  for (int i = 0; i < 32; i += 8)
    out[(size_t)(bc + ty + i) * R + (br + tx)] = f32_to_bf16(tile[tx][ty + i]);
}

// ---------------- embedding gather: E[t][j*256+d] = tab[ctx(t,j)][d] in bf16 ----------------
__global__ void k_gather_e(const int* __restrict__ text,
                           const float* __restrict__ embed,
                           unsigned short* __restrict__ E) {
  int t = blockIdx.x;            // token 0..8191
  int b = t >> 9, s = t & 511;
  int d = threadIdx.x;           // 0..255
#pragma unroll
  for (int j = 0; j < 4; ++j) {
    int sidx = s + j - 4;
    int tok = (sidx >= 0) ? text[b * SS + sidx] : 0;
    float val = (tok != 0) ? embed[(size_t)tok * EMB + d] : 0.0f; // tab[0] = 0
    E[(size_t)t * KDIM + j * EMB + d] = f32_to_bf16(val);
  }
}

// ---------------- bf16 GEMM, A[M][K] row-major, Bt[N][K] row-major (B transposed) --------
// 128x128 tile, BK=32, 4 waves (2x2), mfma_f32_16x16x32_bf16.
// EPI=0: Hout = bf16(relu(C + bias))   EPI=1: fused softmax stats per 64-col chunk
template<int N, int EPI>
__global__ __launch_bounds__(256)
void k_gemm(const unsigned short* __restrict__ A,
            const unsigned short* __restrict__ Bt,
            const float* __restrict__ bias,
            unsigned short* __restrict__ Hout,
            float* __restrict__ pmax, float* __restrict__ psum,
            float* __restrict__ tlog, const int* __restrict__ target) {
  __shared__ unsigned short As[128 * 32]; // [row][32] bf16, 64B rows
  __shared__ unsigned short Bs[128 * 32];
  const int tid  = threadIdx.x;
  const int bn   = blockIdx.x, bm = blockIdx.y;
  const int lane = tid & 63, wid = tid >> 6;
  const int wm = wid >> 1, wn = wid & 1;
  const int g = lane >> 4, c = lane & 15;

  f32x4 acc[4][4];
#pragma unroll
  for (int m = 0; m < 4; ++m)
#pragma unroll
    for (int n = 0; n < 4; ++n) { f32x4 z = {0.f, 0.f, 0.f, 0.f}; acc[m][n] = z; }

  // staging: each thread owns 16B; issue i covers tile rows [i*64, i*64+64)
  const int arow = tid >> 2;           // row within 64-row group
  const int slotb = (tid & 3) * 16;    // byte offset within 64B row
  const char* gA0 = (const char*)A + ((size_t)(bm * 128 + arow) * KDIM) * 2 + slotb;
  const char* gA1 = gA0 + (size_t)64 * KDIM * 2;
  const char* gB0 = (const char*)Bt + ((size_t)(bn * 128 + arow) * KDIM) * 2 + slotb;
  const char* gB1 = gB0 + (size_t)64 * KDIM * 2;
  char* lA = (char*)As + tid * 16;     // linear lane-order dest
  char* lB = (char*)Bs + tid * 16;

  for (int kt = 0; kt < KDIM / 32; ++kt) {
    const int kb = kt * 64; // byte offset along K
    gload_lds16(gA0 + kb, lA);
    gload_lds16(gA1 + kb, lA + 4096);
    gload_lds16(gB0 + kb, lB);
    gload_lds16(gB1 + kb, lB + 4096);
    __syncthreads(); // drains vmcnt -> staged tile visible

    bf16x8 af[4], bf[4];
#pragma unroll
    for (int m = 0; m < 4; ++m)
      af[m] = *(const bf16x8*)&As[(wm * 64 + m * 16 + c) * 32 + g * 8];
#pragma unroll
    for (int n = 0; n < 4; ++n)
      bf[n] = *(const bf16x8*)&Bs[(wn * 64 + n * 16 + c) * 32 + g * 8];
#pragma unroll
    for (int m = 0; m < 4; ++m)
#pragma unroll
      for (int n = 0; n < 4; ++n)
        acc[m][n] = __builtin_amdgcn_mfma_f32_16x16x32_bf16(af[m], bf[n], acc[m][n], 0, 0, 0);
    __syncthreads(); // reads done before restage
  }

  // epilogue. C/D layout: col = lane&15, row = (lane>>4)*4 + reg  [m89-verified]
  if constexpr (EPI == 0) {
#pragma unroll
    for (int n = 0; n < 4; ++n) {
      int colg = bn * 128 + wn * 64 + n * 16 + c;
      float bv = bias[colg];
#pragma unroll
      for (int m = 0; m < 4; ++m)
#pragma unroll
        for (int j = 0; j < 4; ++j) {
          int rowg = bm * 128 + wm * 64 + m * 16 + g * 4 + j;
          float v = acc[m][n][j] + bv;
          v = v > 0.f ? v : 0.f;
          Hout[(size_t)rowg * N + colg] = f32_to_bf16(v);
        }
    }
  } else {
    int chunk = bn * 2 + wn; // 64-col chunk id, 0..499
    float bov[4];
#pragma unroll
    for (int n = 0; n < 4; ++n) bov[n] = bias[bn * 128 + wn * 64 + n * 16 + c];
#pragma unroll
    for (int m = 0; m < 4; ++m) {
#pragma unroll
      for (int j = 0; j < 4; ++j) {
        int rowg = bm * 128 + wm * 64 + m * 16 + g * 4 + j;
        float v0 = acc[m][0][j] + bov[0];
        float v1 = acc[m][1][j] + bov[1];
        float v2 = acc[m][2][j] + bov[2];
        float v3 = acc[m][3][j] + bov[3];
        float mv = fmaxf(fmaxf(v0, v1), fmaxf(v2, v3));
#pragma unroll
        for (int sft = 1; sft < 16; sft <<= 1) mv = fmaxf(mv, __shfl_xor(mv, sft));
        float se = __expf(v0 - mv) + __expf(v1 - mv) + __expf(v2 - mv) + __expf(v3 - mv);
#pragma unroll
        for (int sft = 1; sft < 16; sft <<= 1) se += __shfl_xor(se, sft);
        if (c == 0) {
          pmax[(size_t)rowg * PSTRIDE + chunk] = mv;
          psum[(size_t)rowg * PSTRIDE + chunk] = se;
        }
        int tgt = target[rowg];
        int cw = tgt - (bn * 128 + wn * 64);
        if (cw >= 0 && cw < 64 && c == (cw & 15)) {
          int nn = cw >> 4; // static-select to keep regs
          float tv = (nn == 0) ? v0 : (nn == 1) ? v1 : (nn == 2) ? v2 : v3;
          tlog[rowg] = tv;
        }
      }
    }
  }
}

// ---------------- combine per-chunk stats -> nll per row ----------------
__global__ void k_reduce_nll(const float* __restrict__ pmax,
                             const float* __restrict__ psum,
                             const float* __restrict__ tlog,
                             float* __restrict__ nll) {
  int row = blockIdx.x;
  int lane = threadIdx.x; // 64
  float M = -1e30f;
  for (int ch = lane; ch < NCHUNK; ch += 64) M = fmaxf(M, pmax[(size_t)row * PSTRIDE + ch]);
#pragma unroll
  for (int s = 1; s < 64; s <<= 1) M = fmaxf(M, __shfl_xor(M, s));
  float L = 0.f;
  for (int ch = lane; ch < NCHUNK; ch += 64)
    L += __expf(pmax[(size_t)row * PSTRIDE + ch] - M) * psum[(size_t)row * PSTRIDE + ch];
#pragma unroll
  for (int s = 1; s < 64; s <<= 1) L += __shfl_xor(L, s);
  if (lane == 0) nll[row] = -(tlog[row] - M - logf(L));
}

// ---------------- masked per-step mean -> scalar loss ----------------
__global__ void k_loss(const int* __restrict__ target,
                       const float* __restrict__ nll,
                       float* __restrict__ out) {
  __shared__ float red[SS];
  int s = threadIdx.x; // 512
  float sl = 0.f, cnt = 0.f;
#pragma unroll
  for (int b = 0; b < NB; ++b) {
    int idx = b * SS + s;
    if (target[idx] != 0) { sl += nll[idx]; cnt += 1.f; }
  }
  red[s] = sl / fmaxf(cnt, 1.f);
  __syncthreads();
  for (int st = 256; st > 0; st >>= 1) {
    if (s < st) red[s] += red[s + st];
    __syncthreads();
  }
  if (s == 0) out[0] = red[0] / (float)SS;
}

// ---------------- launch ----------------
extern "C" void kernel_launch(void* const* d_in, const int* in_sizes, int n_in,
                              void* d_out, int out_size, void* d_ws, size_t ws_size,
                              hipStream_t stream) {
  (void)in_sizes; (void)n_in; (void)out_size; (void)ws_size;
  const int*   text   = (const int*)d_in[0];
  const int*   target = (const int*)d_in[1];
  const float* embed  = (const float*)d_in[2];
  const float* W1     = (const float*)d_in[3];
  const float* b1     = (const float*)d_in[4];
  const float* W2     = (const float*)d_in[5];
  const float* b2     = (const float*)d_in[6];
  const float* Wo     = (const float*)d_in[7];
  const float* bo     = (const float*)d_in[8];
  float* out = (float*)d_out;
  char* ws = (char*)d_ws;

  // workspace layout (needs ~114.6 MB)
  const size_t SZ_E = (size_t)MTOK * KDIM * 2;         // 16.78 MB (== 8192*512*4)
  unsigned short* E   = (unsigned short*)(ws);
  unsigned short* H1  = (unsigned short*)(ws + SZ_E);
  unsigned short* H2  = (unsigned short*)(ws + 2 * SZ_E);
  unsigned short* W1t = (unsigned short*)(ws + 3 * SZ_E);
  unsigned short* W2t = (unsigned short*)(ws + 3 * SZ_E + (size_t)HID * HID * 2);
  unsigned short* Wot = (unsigned short*)(ws + 3 * SZ_E + (size_t)2 * HID * HID * 2);
  char* after = ws + 3 * SZ_E + (size_t)2 * HID * HID * 2 + (size_t)VOCAB * HID * 2;
  float* tlog = (float*)after;
  float* nll  = (float*)(after + (size_t)MTOK * 4);
  float* pmax = (float*)E;   // E dead after GEMM1
  float* psum = (float*)H1;  // H1 dead after GEMM2

  k_transpose_bf16<<<dim3(HID / 32, HID / 32), 256, 0, stream>>>(W1, W1t, HID, HID);
  k_transpose_bf16<<<dim3(HID / 32, HID / 32), 256, 0, stream>>>(W2, W2t, HID, HID);
  k_transpose_bf16<<<dim3(VOCAB / 32, HID / 32), 256, 0, stream>>>(Wo, Wot, HID, VOCAB);
  k_gather_e<<<MTOK, 256, 0, stream>>>(text, embed, E);

  k_gemm<HID, 0><<<dim3(HID / 128, MTOK / 128), 256, 0, stream>>>(
      E, W1t, b1, H1, nullptr, nullptr, nullptr, nullptr);
  k_gemm<HID, 0><<<dim3(HID / 128, MTOK / 128), 256, 0, stream>>>(
      H1, W2t, b2, H2, nullptr, nullptr, nullptr, nullptr);
  k_gemm<VOCAB, 1><<<dim3(VOCAB / 128, MTOK / 128), 256, 0, stream>>>(
      H2, Wot, bo, nullptr, pmax, psum, tlog, target);

  k_reduce_nll<<<MTOK, 64, 0, stream>>>(pmax, psum, tlog, nll);
  k_loss<<<1, SS, 0, stream>>>(target, nll, out);
}

// Round 2
// 841.659 us; speedup vs baseline: 1.0739x; 1.0739x over previous
//
#include <hip/hip_runtime.h>
#include <cstdint>
#include <cstddef>

// ---------------- problem constants ----------------
#define VOCAB 32000
#define EMB   256
#define HID   1024
#define NB    16      // batch
#define SS    512     // seq
#define MTOK  (NB*SS) // 8192 tokens
#define KDIM  1024    // NM1*EMB = HID
#define NCHUNK 500    // 32000 / 64 cols per wave-chunk
#define PSTRIDE 512   // padded chunk stride

typedef __bf16 bf16_t;
typedef bf16_t bf16x8 __attribute__((ext_vector_type(8)));
typedef float  f32x4  __attribute__((ext_vector_type(4)));

__device__ __forceinline__ unsigned short f32_to_bf16(float f) {
  union { float f; unsigned int u; } v; v.f = f;
  unsigned int u = v.u;
  unsigned int r = (u + 0x7FFFu + ((u >> 16) & 1u)) >> 16; // RNE
  return (unsigned short)r;
}

// global -> LDS direct copy, 16B per lane. LDS dest must be linear in lane order.
__device__ __forceinline__ void gload_lds16(const void* gsrc, void* ldst) {
  __builtin_amdgcn_global_load_lds(
      (__attribute__((address_space(1))) void*)gsrc,
      (__attribute__((address_space(3))) void*)ldst,
      16, 0, 0);
}

#define MEMFENCE asm volatile("" ::: "memory")

// ---------------- transpose + f32->bf16 convert: in[R][C] -> out[C][R] ----------------
__global__ void k_transpose_bf16(const float* __restrict__ in,
                                 unsigned short* __restrict__ out,
                                 int R, int C) {
  __shared__ float tile[32][33];
  int bc = blockIdx.x * 32, br = blockIdx.y * 32;
  int tx = threadIdx.x & 31, ty = threadIdx.x >> 5; // 256 threads
#pragma unroll
  for (int i = 0; i < 32; i += 8)
    tile[ty + i][tx] = in[(size_t)(br + ty + i) * C + (bc + tx)];
  __syncthreads();
#pragma unroll
  for (int i = 0; i < 32; i += 8)
    out[(size_t)(bc + ty + i) * R + (br + tx)] = f32_to_bf16(tile[tx][ty + i]);
}

// ---------------- embedding gather ----------------
__global__ void k_gather_e(const int* __restrict__ text,
                           const float* __restrict__ embed,
                           unsigned short* __restrict__ E) {
  int t = blockIdx.x;
  int b = t >> 9, s = t & 511;
  int d = threadIdx.x; // 0..255
#pragma unroll
  for (int j = 0; j < 4; ++j) {
    int sidx = s + j - 4;
    int tok = (sidx >= 0) ? text[b * SS + sidx] : 0;
    float val = (tok != 0) ? embed[(size_t)tok * EMB + d] : 0.0f;
    E[(size_t)t * KDIM + j * EMB + d] = f32_to_bf16(val);
  }
}

// ---------------- FFN GEMM (128x128 tile, relu+bias epilogue) ----------------
// LDS slot-XOR swizzle: LDS slot lq of row r holds global slot lq ^ ((r>>1)&3)
// (pre-swizzled source on stage, XOR on read; 64 lanes -> 8 lanes/bank-quad, conflict-free)
__global__ __launch_bounds__(256)
void k_gemm_ffn(const unsigned short* __restrict__ A,
                const unsigned short* __restrict__ Bt,
                const float* __restrict__ bias,
                unsigned short* __restrict__ Hout, int N) {
  __shared__ unsigned short As[128 * 32];
  __shared__ unsigned short Bs[128 * 32];
  const int tid  = threadIdx.x;
  const int bn   = blockIdx.x, bm = blockIdx.y;
  const int lane = tid & 63, wid = tid >> 6;
  const int wm = wid >> 1, wn = wid & 1;
  const int g = lane >> 4, c = lane & 15;

  f32x4 acc[4][4];
#pragma unroll
  for (int m = 0; m < 4; ++m)
#pragma unroll
    for (int n = 0; n < 4; ++n) { f32x4 z = {0.f, 0.f, 0.f, 0.f}; acc[m][n] = z; }

  const int arow = tid >> 2;
  const int slotb = ((tid & 3) ^ ((tid >> 3) & 3)) * 16; // pre-swizzled source slot
  const char* gA0 = (const char*)A + ((size_t)(bm * 128 + arow) * KDIM) * 2 + slotb;
  const char* gA1 = gA0 + (size_t)64 * KDIM * 2;
  const char* gB0 = (const char*)Bt + ((size_t)(bn * 128 + arow) * KDIM) * 2 + slotb;
  const char* gB1 = gB0 + (size_t)64 * KDIM * 2;
  char* lA = (char*)As + tid * 16;
  char* lB = (char*)Bs + tid * 16;

  const int rs = (g ^ ((c >> 1) & 3)) * 8; // swizzled read slot (ushort idx)

  for (int kt = 0; kt < KDIM / 32; ++kt) {
    const int kb = kt * 64;
    gload_lds16(gA0 + kb, lA);
    gload_lds16(gA1 + kb, lA + 4096);
    gload_lds16(gB0 + kb, lB);
    gload_lds16(gB1 + kb, lB + 4096);
    __syncthreads();

    bf16x8 af[4], bf[4];
#pragma unroll
    for (int m = 0; m < 4; ++m)
      af[m] = *(const bf16x8*)&As[(wm * 64 + m * 16 + c) * 32 + rs];
#pragma unroll
    for (int n = 0; n < 4; ++n)
      bf[n] = *(const bf16x8*)&Bs[(wn * 64 + n * 16 + c) * 32 + rs];
#pragma unroll
    for (int m = 0; m < 4; ++m)
#pragma unroll
      for (int n = 0; n < 4; ++n)
        acc[m][n] = __builtin_amdgcn_mfma_f32_16x16x32_bf16(af[m], bf[n], acc[m][n], 0, 0, 0);
    __syncthreads();
  }

#pragma unroll
  for (int n = 0; n < 4; ++n) {
    int colg = bn * 128 + wn * 64 + n * 16 + c;
    float bv = bias[colg];
#pragma unroll
    for (int m = 0; m < 4; ++m)
#pragma unroll
      for (int j = 0; j < 4; ++j) {
        int rowg = bm * 128 + wm * 64 + m * 16 + g * 4 + j;
        float v = acc[m][n][j] + bv;
        v = v > 0.f ? v : 0.f;
        Hout[(size_t)rowg * N + colg] = f32_to_bf16(v);
      }
  }
}

// ---------------- vocab GEMM: 256x256 tile, BK=64, 8 waves, deep pipeline ----------------
// Double-buffered LDS (2 x (A 32KB + B 32KB) = 128KB). Burst-stage K-tile T+2 at the
// end-of-window-T boundary (slot freed by the reads-done barrier), counted vmcnt(8)
// keeps next tile's 8 loads in flight. 4 phases/window = C-quadrants, raw s_barrier.
// LDS [256][64] bf16: quad-XOR swizzle q' = q ^ (row&7) (read side), pre-swizzled source.
__global__ __launch_bounds__(512, 2)
void k_gemm_vocab(const unsigned short* __restrict__ A,
                  const unsigned short* __restrict__ Bt,
                  const float* __restrict__ bias,
                  float* __restrict__ pmax, float* __restrict__ psum,
                  float* __restrict__ tlog, const int* __restrict__ target) {
  __shared__ unsigned short As[2][256 * 64];
  __shared__ unsigned short Bs[2][256 * 64];
  const int tid  = threadIdx.x;
  const int lane = tid & 63, wid = tid >> 6;   // 8 waves
  const int wm = wid >> 2, wn = wid & 3;       // 2 (M) x 4 (N)
  const int g = lane >> 4, c = lane & 15;

  // bijective supertile (4bm x 5bn) XCD-chunked block swizzle; grid = 4000 = 32 x 125
  {
  }
  const int o   = blockIdx.x;
  const int xcd = o & 7, kk0 = o >> 3;         // kk0 in [0,500)
  const int gst = xcd * 25 + (kk0 / 20);       // [0,200) global supertile
  const int within = kk0 % 20;
  const int stm = gst & 7, stn = gst >> 3;     // 8 x 25
  const int bm = stm * 4 + (within / 5);       // [0,32)
  const int bn = stn * 5 + (within % 5);       // [0,125)

  f32x4 acc[8][4];
#pragma unroll
  for (int m = 0; m < 8; ++m)
#pragma unroll
    for (int n = 0; n < 4; ++n) { f32x4 z = {0.f, 0.f, 0.f, 0.f}; acc[m][n] = z; }

  // ---- staging addresses: per thread 16B, 4 issues/operand (64 rows each) ----
  const int r64 = tid >> 3, lq = tid & 7;
  const int srcq = lq ^ (r64 & 7);             // pre-swizzled source quad
  const char* gA = (const char*)(A  + (size_t)(bm * 256 + r64) * KDIM) + srcq * 16;
  const char* gB = (const char*)(Bt + (size_t)(bn * 256 + r64) * KDIM) + srcq * 16;
  // issue stride: 64 rows = 64*1024*2 = 131072 B; K-tile stride: 64 cols = 128 B

#define STAGE(t, d) do {                                                   \
    const char* sa = gA + (size_t)(t) * 128;                               \
    const char* sb = gB + (size_t)(t) * 128;                               \
    char* la = (char*)&As[d][0] + tid * 16;                                \
    char* lb = (char*)&Bs[d][0] + tid * 16;                                \
    gload_lds16(sa,          la);                                          \
    gload_lds16(sa + 131072, la + 8192);                                   \
    gload_lds16(sa + 262144, la + 16384);                                  \
    gload_lds16(sa + 393216, la + 24576);                                  \
    gload_lds16(sb,          lb);                                          \
    gload_lds16(sb + 131072, lb + 8192);                                   \
    gload_lds16(sb + 262144, lb + 16384);                                  \
    gload_lds16(sb + 393216, lb + 24576);                                  \
  } while (0)

  // ---- LDS read offsets (bytes). row&7 == c&7; data quad q = kk*4+g ----
  const int q7 = c & 7;
  const int baseA = (wm * 128 + c) * 128;  // + (mh*64+mf*16)*128 + ((kk*4+g)^q7)*16
  const int baseB = (wn * 64 + c) * 128;   // + (nf*16)*128        + ((kk*4+g)^q7)*16

#define LDA(mh, mf, kk) (*(const bf16x8*)((const char*)Ab + baseA + ((mh)*64 + (mf)*16) * 128 + ((((kk)*4 + g) ^ q7) << 4)))
#define LDB(nf, kk)     (*(const bf16x8*)((const char*)Bb + baseB + ((nf)*16) * 128 + ((((kk)*4 + g) ^ q7) << 4)))

  const int NT = KDIM / 64; // 16
  // prologue: stage tiles 0,1; wait tile 0 (8 newest stay in flight)
  STAGE(0, 0);
  STAGE(1, 1);
  asm volatile("s_waitcnt vmcnt(8)" ::: "memory");
  __builtin_amdgcn_s_barrier();
  MEMFENCE;

  for (int T = 0; T < NT; ++T) {
    const unsigned short* Ab = As[T & 1];
    const unsigned short* Bb = Bs[T & 1];
    bf16x8 a[4][2], b[4][2];

    // ---- phase 0: quadrant (mh=0, nh=0); 8 A-reads + 4 B-reads ----
#pragma unroll
    for (int mf = 0; mf < 4; ++mf)
#pragma unroll
      for (int kk = 0; kk < 2; ++kk) a[mf][kk] = LDA(0, mf, kk);
#pragma unroll
    for (int nf = 0; nf < 2; ++nf)
#pragma unroll
      for (int kk = 0; kk < 2; ++kk) b[nf][kk] = LDB(nf, kk);
    __builtin_amdgcn_s_setprio(1);
#pragma unroll
    for (int mf = 0; mf < 4; ++mf)
#pragma unroll
      for (int nf = 0; nf < 2; ++nf)
#pragma unroll
        for (int kk = 0; kk < 2; ++kk)
          acc[mf][nf] = __builtin_amdgcn_mfma_f32_16x16x32_bf16(a[mf][kk], b[nf][kk], acc[mf][nf], 0, 0, 0);
    __builtin_amdgcn_s_setprio(0);
    MEMFENCE; __builtin_amdgcn_s_barrier(); MEMFENCE;

    // ---- phase 1: quadrant (mh=0, nh=1); 4 B-reads ----
#pragma unroll
    for (int nf = 0; nf < 2; ++nf)
#pragma unroll
      for (int kk = 0; kk < 2; ++kk) b[2 + nf][kk] = LDB(2 + nf, kk);
    __builtin_amdgcn_s_setprio(1);
#pragma unroll
    for (int mf = 0; mf < 4; ++mf)
#pragma unroll
      for (int nf = 0; nf < 2; ++nf)
#pragma unroll
        for (int kk = 0; kk < 2; ++kk)
          acc[mf][2 + nf] = __builtin_amdgcn_mfma_f32_16x16x32_bf16(a[mf][kk], b[2 + nf][kk], acc[mf][2 + nf], 0, 0, 0);
    __builtin_amdgcn_s_setprio(0);
    MEMFENCE; __builtin_amdgcn_s_barrier(); MEMFENCE;

    // ---- phase 2: quadrant (mh=1, nh=0); 8 A-reads ----
#pragma unroll
    for (int mf = 0; mf < 4; ++mf)
#pragma unroll
      for (int kk = 0; kk < 2; ++kk) a[mf][kk] = LDA(1, mf, kk);
    __builtin_amdgcn_s_setprio(1);
#pragma unroll
    for (int mf = 0; mf < 4; ++mf)
#pragma unroll
      for (int nf = 0; nf < 2; ++nf)
#pragma unroll
        for (int kk = 0; kk < 2; ++kk)
          acc[4 + mf][nf] = __builtin_amdgcn_mfma_f32_16x16x32_bf16(a[mf][kk], b[nf][kk], acc[4 + mf][nf], 0, 0, 0);
    __builtin_amdgcn_s_setprio(0);
    MEMFENCE; __builtin_amdgcn_s_barrier(); MEMFENCE;

    // ---- phase 3: quadrant (mh=1, nh=1); no reads ----
    __builtin_amdgcn_s_setprio(1);
#pragma unroll
    for (int mf = 0; mf < 4; ++mf)
#pragma unroll
      for (int nf = 0; nf < 2; ++nf)
#pragma unroll
        for (int kk = 0; kk < 2; ++kk)
          acc[4 + mf][2 + nf] = __builtin_amdgcn_mfma_f32_16x16x32_bf16(a[mf][kk], b[2 + nf][kk], acc[4 + mf][2 + nf], 0, 0, 0);
    __builtin_amdgcn_s_setprio(0);

    // ---- boundary: free slot (reads done), restage 2-ahead, counted wait ----
    if (T + 1 < NT) {
      MEMFENCE; __builtin_amdgcn_s_barrier(); MEMFENCE;   // all reads of buf[T&1] done
      if (T + 2 < NT) {
        STAGE(T + 2, T & 1);
        asm volatile("s_waitcnt vmcnt(8)" ::: "memory");  // tile T+1 landed; T+2 in flight
      } else {
        asm volatile("s_waitcnt vmcnt(0)" ::: "memory");  // tail: tile T+1 landed
      }
      __builtin_amdgcn_s_barrier();                       // all waves' loads visible
      MEMFENCE;
    }
  }
#undef STAGE
#undef LDA
#undef LDB

  // ---- epilogue: fused softmax stats per 64-col chunk ----
  const int chunk = bn * 4 + wn;
  float bov[4];
#pragma unroll
  for (int n = 0; n < 4; ++n) bov[n] = bias[bn * 256 + wn * 64 + n * 16 + c];
#pragma unroll
  for (int m = 0; m < 8; ++m) {
#pragma unroll
    for (int j = 0; j < 4; ++j) {
      int rowg = bm * 256 + wm * 128 + m * 16 + g * 4 + j;
      float v0 = acc[m][0][j] + bov[0];
      float v1 = acc[m][1][j] + bov[1];
      float v2 = acc[m][2][j] + bov[2];
      float v3 = acc[m][3][j] + bov[3];
      float mv = fmaxf(fmaxf(v0, v1), fmaxf(v2, v3));
#pragma unroll
      for (int sft = 1; sft < 16; sft <<= 1) mv = fmaxf(mv, __shfl_xor(mv, sft));
      float se = __expf(v0 - mv) + __expf(v1 - mv) + __expf(v2 - mv) + __expf(v3 - mv);
#pragma unroll
      for (int sft = 1; sft < 16; sft <<= 1) se += __shfl_xor(se, sft);
      if (c == 0) {
        pmax[(size_t)rowg * PSTRIDE + chunk] = mv;
        psum[(size_t)rowg * PSTRIDE + chunk] = se;
      }
      int tgt = target[rowg];
      int cw = tgt - (bn * 256 + wn * 64);
      if (cw >= 0 && cw < 64 && c == (cw & 15)) {
        int nn = cw >> 4;
        float tv = (nn == 0) ? v0 : (nn == 1) ? v1 : (nn == 2) ? v2 : v3;
        tlog[rowg] = tv;
      }
    }
  }
}

// ---------------- combine per-chunk stats -> nll per row ----------------
__global__ void k_reduce_nll(const float* __restrict__ pmax,
                             const float* __restrict__ psum,
                             const float* __restrict__ tlog,
                             float* __restrict__ nll) {
  int row = blockIdx.x;
  int lane = threadIdx.x; // 64
  float M = -1e30f;
  for (int ch = lane; ch < NCHUNK; ch += 64) M = fmaxf(M, pmax[(size_t)row * PSTRIDE + ch]);
#pragma unroll
  for (int s = 1; s < 64; s <<= 1) M = fmaxf(M, __shfl_xor(M, s));
  float L = 0.f;
  for (int ch = lane; ch < NCHUNK; ch += 64)
    L += __expf(pmax[(size_t)row * PSTRIDE + ch] - M) * psum[(size_t)row * PSTRIDE + ch];
#pragma unroll
  for (int s = 1; s < 64; s <<= 1) L += __shfl_xor(L, s);
  if (lane == 0) nll[row] = -(tlog[row] - M - logf(L));
}

// ---------------- masked per-step mean -> scalar loss ----------------
__global__ void k_loss(const int* __restrict__ target,
                       const float* __restrict__ nll,
                       float* __restrict__ out) {
  __shared__ float red[SS];
  int s = threadIdx.x; // 512
  float sl = 0.f, cnt = 0.f;
#pragma unroll
  for (int b = 0; b < NB; ++b) {
    int idx = b * SS + s;
    if (target[idx] != 0) { sl += nll[idx]; cnt += 1.f; }
  }
  red[s] = sl / fmaxf(cnt, 1.f);
  __syncthreads();
  for (int st = 256; st > 0; st >>= 1) {
    if (s < st) red[s] += red[s + st];
    __syncthreads();
  }
  if (s == 0) out[0] = red[0] / (float)SS;
}

// ---------------- launch ----------------
extern "C" void kernel_launch(void* const* d_in, const int* in_sizes, int n_in,
                              void* d_out, int out_size, void* d_ws, size_t ws_size,
                              hipStream_t stream) {
  (void)in_sizes; (void)n_in; (void)out_size; (void)ws_size;
  const int*   text   = (const int*)d_in[0];
  const int*   target = (const int*)d_in[1];
  const float* embed  = (const float*)d_in[2];
  const float* W1     = (const float*)d_in[3];
  const float* b1     = (const float*)d_in[4];
  const float* W2     = (const float*)d_in[5];
  const float* b2     = (const float*)d_in[6];
  const float* Wo     = (const float*)d_in[7];
  const float* bo     = (const float*)d_in[8];
  float* out = (float*)d_out;
  char* ws = (char*)d_ws;

  const size_t SZ_E = (size_t)MTOK * KDIM * 2; // 16.78 MB
  unsigned short* E   = (unsigned short*)(ws);
  unsigned short* H1  = (unsigned short*)(ws + SZ_E);
  unsigned short* H2  = (unsigned short*)(ws + 2 * SZ_E);
  unsigned short* W1t = (unsigned short*)(ws + 3 * SZ_E);
  unsigned short* W2t = (unsigned short*)(ws + 3 * SZ_E + (size_t)HID * HID * 2);
  unsigned short* Wot = (unsigned short*)(ws + 3 * SZ_E + (size_t)2 * HID * HID * 2);
  char* after = ws + 3 * SZ_E + (size_t)2 * HID * HID * 2 + (size_t)VOCAB * HID * 2;
  float* tlog = (float*)after;
  float* nll  = (float*)(after + (size_t)MTOK * 4);
  float* pmax = (float*)E;   // E dead after GEMM1
  float* psum = (float*)H1;  // H1 dead after GEMM2

  k_transpose_bf16<<<dim3(HID / 32, HID / 32), 256, 0, stream>>>(W1, W1t, HID, HID);
  k_transpose_bf16<<<dim3(HID / 32, HID / 32), 256, 0, stream>>>(W2, W2t, HID, HID);
  k_transpose_bf16<<<dim3(VOCAB / 32, HID / 32), 256, 0, stream>>>(Wo, Wot, HID, VOCAB);
  k_gather_e<<<MTOK, 256, 0, stream>>>(text, embed, E);

  k_gemm_ffn<<<dim3(HID / 128, MTOK / 128), 256, 0, stream>>>(E, W1t, b1, H1, HID);
  k_gemm_ffn<<<dim3(HID / 128, MTOK / 128), 256, 0, stream>>>(H1, W2t, b2, H2, HID);

  k_gemm_vocab<<<dim3((MTOK / 256) * (VOCAB / 256)), 512, 0, stream>>>(
      H2, Wot, bo, pmax, psum, tlog, target);

  k_reduce_nll<<<MTOK, 64, 0, stream>>>(pmax, psum, tlog, nll);
  k_loss<<<1, SS, 0, stream>>>(target, nll, out);
}

// Round 3
// 767.003 us; speedup vs baseline: 1.1785x; 1.0973x over previous
//
#include <hip/hip_runtime.h>
#include <cstdint>
#include <cstddef>

// ---------------- problem constants ----------------
#define VOCAB 32000
#define EMB   256
#define HID   1024
#define NB    16      // batch
#define SS    512     // seq
#define MTOK  (NB*SS) // 8192 tokens
#define KDIM  1024    // NM1*EMB = HID
#define NCHUNK 500    // 32000 / 64 cols per wave-chunk
#define PSTRIDE 512   // padded chunk stride

typedef __bf16 bf16_t;
typedef bf16_t bf16x8 __attribute__((ext_vector_type(8)));
typedef float  f32x4  __attribute__((ext_vector_type(4)));

__device__ __forceinline__ unsigned short f32_to_bf16(float f) {
  union { float f; unsigned int u; } v; v.f = f;
  unsigned int u = v.u;
  unsigned int r = (u + 0x7FFFu + ((u >> 16) & 1u)) >> 16; // RNE
  return (unsigned short)r;
}

__device__ __forceinline__ void gload_lds16(const void* gsrc, void* ldst) {
  __builtin_amdgcn_global_load_lds(
      (__attribute__((address_space(1))) void*)gsrc,
      (__attribute__((address_space(3))) void*)ldst,
      16, 0, 0);
}

#define MEMFENCE asm volatile("" ::: "memory")
#define PH_BAR do { MEMFENCE; __builtin_amdgcn_s_barrier(); MEMFENCE; } while (0)

// ---------------- transpose + f32->bf16 convert: in[R][C] -> out[C][R] ----------------
__global__ void k_transpose_bf16(const float* __restrict__ in,
                                 unsigned short* __restrict__ out,
                                 int R, int C) {
  __shared__ float tile[32][33];
  int bc = blockIdx.x * 32, br = blockIdx.y * 32;
  int tx = threadIdx.x & 31, ty = threadIdx.x >> 5;
#pragma unroll
  for (int i = 0; i < 32; i += 8)
    tile[ty + i][tx] = in[(size_t)(br + ty + i) * C + (bc + tx)];
  __syncthreads();
#pragma unroll
  for (int i = 0; i < 32; i += 8)
    out[(size_t)(bc + ty + i) * R + (br + tx)] = f32_to_bf16(tile[tx][ty + i]);
}

// ---------------- embedding gather ----------------
__global__ void k_gather_e(const int* __restrict__ text,
                           const float* __restrict__ embed,
                           unsigned short* __restrict__ E) {
  int t = blockIdx.x;
  int b = t >> 9, s = t & 511;
  int d = threadIdx.x; // 0..255
#pragma unroll
  for (int j = 0; j < 4; ++j) {
    int sidx = s + j - 4;
    int tok = (sidx >= 0) ? text[b * SS + sidx] : 0;
    float val = (tok != 0) ? embed[(size_t)tok * EMB + d] : 0.0f;
    E[(size_t)t * KDIM + j * EMB + d] = f32_to_bf16(val);
  }
}

// ---------------- FFN GEMM (128x128 tile, relu+bias epilogue) ----------------
__global__ __launch_bounds__(256)
void k_gemm_ffn(const unsigned short* __restrict__ A,
                const unsigned short* __restrict__ Bt,
                const float* __restrict__ bias,
                unsigned short* __restrict__ Hout, int N) {
  __shared__ unsigned short As[128 * 32];
  __shared__ unsigned short Bs[128 * 32];
  const int tid  = threadIdx.x;
  const int bn   = blockIdx.x, bm = blockIdx.y;
  const int lane = tid & 63, wid = tid >> 6;
  const int wm = wid >> 1, wn = wid & 1;
  const int g = lane >> 4, c = lane & 15;

  f32x4 acc[4][4];
#pragma unroll
  for (int m = 0; m < 4; ++m)
#pragma unroll
    for (int n = 0; n < 4; ++n) { f32x4 z = {0.f, 0.f, 0.f, 0.f}; acc[m][n] = z; }

  const int arow = tid >> 2;
  const int slotb = ((tid & 3) ^ ((tid >> 3) & 3)) * 16;
  const char* gA0 = (const char*)A + ((size_t)(bm * 128 + arow) * KDIM) * 2 + slotb;
  const char* gA1 = gA0 + (size_t)64 * KDIM * 2;
  const char* gB0 = (const char*)Bt + ((size_t)(bn * 128 + arow) * KDIM) * 2 + slotb;
  const char* gB1 = gB0 + (size_t)64 * KDIM * 2;
  char* lA = (char*)As + tid * 16;
  char* lB = (char*)Bs + tid * 16;

  const int rs = (g ^ ((c >> 1) & 3)) * 8;

  for (int kt = 0; kt < KDIM / 32; ++kt) {
    const int kb = kt * 64;
    gload_lds16(gA0 + kb, lA);
    gload_lds16(gA1 + kb, lA + 4096);
    gload_lds16(gB0 + kb, lB);
    gload_lds16(gB1 + kb, lB + 4096);
    __syncthreads();

    bf16x8 af[4], bf[4];
#pragma unroll
    for (int m = 0; m < 4; ++m)
      af[m] = *(const bf16x8*)&As[(wm * 64 + m * 16 + c) * 32 + rs];
#pragma unroll
    for (int n = 0; n < 4; ++n)
      bf[n] = *(const bf16x8*)&Bs[(wn * 64 + n * 16 + c) * 32 + rs];
#pragma unroll
    for (int m = 0; m < 4; ++m)
#pragma unroll
      for (int n = 0; n < 4; ++n)
        acc[m][n] = __builtin_amdgcn_mfma_f32_16x16x32_bf16(af[m], bf[n], acc[m][n], 0, 0, 0);
    __syncthreads();
  }

#pragma unroll
  for (int n = 0; n < 4; ++n) {
    int colg = bn * 128 + wn * 64 + n * 16 + c;
    float bv = bias[colg];
#pragma unroll
    for (int m = 0; m < 4; ++m)
#pragma unroll
      for (int j = 0; j < 4; ++j) {
        int rowg = bm * 128 + wm * 64 + m * 16 + g * 4 + j;
        float v = acc[m][n][j] + bv;
        v = v > 0.f ? v : 0.f;
        Hout[(size_t)rowg * N + colg] = f32_to_bf16(v);
      }
  }
}

// ---------------- vocab GEMM: 256x256, BK=64, 8 waves, m201-style 8-phase ----------------
// LDS: [dbuf][half(128 rows)][128][64] for A and B = 128 KiB. One half-tile (2 gloads)
// staged per phase; counted vmcnt(6) gates at phases 3 and 7 only (3 half-tiles in flight).
__global__ __launch_bounds__(512, 2)
void k_gemm_vocab(const unsigned short* __restrict__ A,
                  const unsigned short* __restrict__ Bt,
                  const float* __restrict__ bias,
                  float* __restrict__ pmax, float* __restrict__ psum,
                  float* __restrict__ tlog, const int* __restrict__ target) {
  __shared__ unsigned short Al[2][2][128 * 64];
  __shared__ unsigned short Bl[2][2][128 * 64];
  const int tid  = threadIdx.x;
  const int lane = tid & 63, wid = tid >> 6;   // 8 waves
  const int wm = wid >> 2, wn = wid & 3;       // 2 (M) x 4 (N)
  const int g = lane >> 4, c = lane & 15;

  // bijective supertile XCD swizzle; grid = 4000 = 32(bm) x 125(bn)
  const int o   = blockIdx.x;
  const int xcd = o & 7, kk0 = o >> 3;
  const int gst = xcd * 25 + (kk0 / 20);
  const int within = kk0 % 20;
  const int stm = gst & 7, stn = gst >> 3;
  const int bm = stm * 4 + (within / 5);
  const int bn = stn * 5 + (within % 5);

  f32x4 acc[8][4];
#pragma unroll
  for (int m = 0; m < 8; ++m)
#pragma unroll
    for (int n = 0; n < 4; ++n) { f32x4 z = {0.f, 0.f, 0.f, 0.f}; acc[m][n] = z; }

  // ---- staging: thread t covers row (t>>3), quad (t&7); pre-swizzled source quad ----
  const int r64 = tid >> 3, lq = tid & 7;
  const int srcq = lq ^ (r64 & 7);
  const char* gA = (const char*)A  + ((size_t)(bm * 256 + r64) * KDIM) * 2 + srcq * 16;
  const char* gB = (const char*)Bt + ((size_t)(bn * 256 + r64) * KDIM) * 2 + srcq * 16;
  // bytes: row stride 2048, half offset 128*2048=262144, issue offset 64*2048=131072,
  // K-tile offset t*128.

#define STAGE_A(t, h) do {                                               \
    const char* s_ = gA + (size_t)(t) * 128 + (size_t)(h) * 262144;      \
    char* d_ = (char*)&Al[(t) & 1][h][0] + tid * 16;                     \
    gload_lds16(s_, d_);                                                 \
    gload_lds16(s_ + 131072, d_ + 8192);                                 \
  } while (0)
#define STAGE_B(t, h) do {                                               \
    const char* s_ = gB + (size_t)(t) * 128 + (size_t)(h) * 262144;      \
    char* d_ = (char*)&Bl[(t) & 1][h][0] + tid * 16;                     \
    gload_lds16(s_, d_);                                                 \
    gload_lds16(s_ + 131072, d_ + 8192);                                 \
  } while (0)

  // ---- LDS reads: A half = wm, local row = mh*64+mf*16+c; B half = wn>>1 ----
  const int q7 = c & 7;
#define LDA(buf, mh, mf, kk) (*(const bf16x8*)((const char*)&Al[buf][wm][0]      + ((mh)*64 + (mf)*16 + c) * 128 + ((((kk)*4 + g) ^ q7) << 4)))
#define LDB(buf, nf, kk)     (*(const bf16x8*)((const char*)&Bl[buf][wn >> 1][0] + ((wn & 1)*64 + (nf)*16 + c) * 128 + ((((kk)*4 + g) ^ q7) << 4)))

#define RD_A(buf, mh) do {                                               \
    _Pragma("unroll") for (int mf = 0; mf < 4; ++mf)                     \
    _Pragma("unroll") for (int kk = 0; kk < 2; ++kk)                     \
      a[mf][kk] = LDA(buf, mh, mf, kk);                                  \
  } while (0)
#define RD_B(buf, nh) do {                                               \
    _Pragma("unroll") for (int nf = 0; nf < 2; ++nf)                     \
    _Pragma("unroll") for (int kk = 0; kk < 2; ++kk)                     \
      b[2*(nh) + nf][kk] = LDB(buf, 2*(nh) + nf, kk);                    \
  } while (0)
#define MFMA_Q(mh, nh) do {                                              \
    __builtin_amdgcn_s_setprio(1);                                       \
    _Pragma("unroll") for (int mf = 0; mf < 4; ++mf)                     \
    _Pragma("unroll") for (int nf = 0; nf < 2; ++nf)                     \
    _Pragma("unroll") for (int kk = 0; kk < 2; ++kk)                     \
      acc[4*(mh) + mf][2*(nh) + nf] = __builtin_amdgcn_mfma_f32_16x16x32_bf16( \
          a[mf][kk], b[2*(nh) + nf][kk], acc[4*(mh) + mf][2*(nh) + nf], 0, 0, 0); \
    __builtin_amdgcn_s_setprio(0);                                       \
  } while (0)

  // ---- prologue: tile0 all 4 halves + tile1 {A0,B0,B1}; 6 newest stay in flight ----
  STAGE_A(0, 0); STAGE_B(0, 0); STAGE_A(0, 1); STAGE_B(0, 1);
  STAGE_A(1, 0); STAGE_B(1, 0); STAGE_B(1, 1);
  asm volatile("s_waitcnt vmcnt(6)" ::: "memory");
  __builtin_amdgcn_s_barrier();
  MEMFENCE;

#pragma unroll 1
  for (int i = 0; i < 8; ++i) {
    bf16x8 a[4][2], b[4][2];
    const int t2 = 2 * i + 2, t3 = 2 * i + 3;
    const bool st = (i < 7);

    // ph0: tile 2i (buf0) Q(0,0); stage A1(2i+1)->buf1
    RD_A(0, 0); RD_B(0, 0);
    STAGE_A(2 * i + 1, 1);
    PH_BAR; MFMA_Q(0, 0); PH_BAR;

    // ph1: Q(0,1); stage A0(t2)->buf0
    RD_B(0, 1);
    if (st) STAGE_A(t2, 0);
    PH_BAR; MFMA_Q(0, 1); PH_BAR;

    // ph2: Q(1,0); stage B0(t2)
    RD_A(0, 1);
    if (st) STAGE_B(t2, 0);
    PH_BAR; MFMA_Q(1, 0); PH_BAR;

    // ph3: Q(1,1); stage B1(t2); gate for tile 2i+1
    if (st) STAGE_B(t2, 1);
    PH_BAR; MFMA_Q(1, 1);
    if (st) asm volatile("s_waitcnt vmcnt(6)" ::: "memory");
    else    asm volatile("s_waitcnt vmcnt(0)" ::: "memory");
    PH_BAR;

    // ph4: tile 2i+1 (buf1) Q(0,0); stage A1(t2)
    RD_A(1, 0); RD_B(1, 0);
    if (st) STAGE_A(t2, 1);
    PH_BAR; MFMA_Q(0, 0); PH_BAR;

    // ph5: Q(0,1); stage A0(t3)->buf1
    RD_B(1, 1);
    if (st) STAGE_A(t3, 0);
    PH_BAR; MFMA_Q(0, 1); PH_BAR;

    // ph6: Q(1,0); stage B0(t3)
    RD_A(1, 1);
    if (st) STAGE_B(t3, 0);
    PH_BAR; MFMA_Q(1, 0); PH_BAR;

    // ph7: Q(1,1); stage B1(t3); gate for tile t2 (next iter ph0)
    if (st) STAGE_B(t3, 1);
    PH_BAR; MFMA_Q(1, 1);
    if (st) {
      asm volatile("s_waitcnt vmcnt(6)" ::: "memory");
      PH_BAR;
    }
  }
#undef STAGE_A
#undef STAGE_B
#undef LDA
#undef LDB
#undef RD_A
#undef RD_B
#undef MFMA_Q

  // ---- epilogue: fused softmax stats per 64-col chunk ----
  const int chunk = bn * 4 + wn;
  float bov[4];
#pragma unroll
  for (int n = 0; n < 4; ++n) bov[n] = bias[bn * 256 + wn * 64 + n * 16 + c];
#pragma unroll
  for (int m = 0; m < 8; ++m) {
#pragma unroll
    for (int j = 0; j < 4; ++j) {
      int rowg = bm * 256 + wm * 128 + m * 16 + g * 4 + j;
      float v0 = acc[m][0][j] + bov[0];
      float v1 = acc[m][1][j] + bov[1];
      float v2 = acc[m][2][j] + bov[2];
      float v3 = acc[m][3][j] + bov[3];
      float mv = fmaxf(fmaxf(v0, v1), fmaxf(v2, v3));
#pragma unroll
      for (int sft = 1; sft < 16; sft <<= 1) mv = fmaxf(mv, __shfl_xor(mv, sft));
      float se = __expf(v0 - mv) + __expf(v1 - mv) + __expf(v2 - mv) + __expf(v3 - mv);
#pragma unroll
      for (int sft = 1; sft < 16; sft <<= 1) se += __shfl_xor(se, sft);
      if (c == 0) {
        pmax[(size_t)rowg * PSTRIDE + chunk] = mv;
        psum[(size_t)rowg * PSTRIDE + chunk] = se;
      }
      int tgt = target[rowg];
      int cw = tgt - (bn * 256 + wn * 64);
      if (cw >= 0 && cw < 64 && c == (cw & 15)) {
        int nn = cw >> 4;
        float tv = (nn == 0) ? v0 : (nn == 1) ? v1 : (nn == 2) ? v2 : v3;
        tlog[rowg] = tv;
      }
    }
  }
}

// ---------------- combine per-chunk stats -> nll per row ----------------
__global__ void k_reduce_nll(const float* __restrict__ pmax,
                             const float* __restrict__ psum,
                             const float* __restrict__ tlog,
                             float* __restrict__ nll) {
  int row = blockIdx.x;
  int lane = threadIdx.x; // 64
  float M = -1e30f;
  for (int ch = lane; ch < NCHUNK; ch += 64) M = fmaxf(M, pmax[(size_t)row * PSTRIDE + ch]);
#pragma unroll
  for (int s = 1; s < 64; s <<= 1) M = fmaxf(M, __shfl_xor(M, s));
  float L = 0.f;
  for (int ch = lane; ch < NCHUNK; ch += 64)
    L += __expf(pmax[(size_t)row * PSTRIDE + ch] - M) * psum[(size_t)row * PSTRIDE + ch];
#pragma unroll
  for (int s = 1; s < 64; s <<= 1) L += __shfl_xor(L, s);
  if (lane == 0) nll[row] = -(tlog[row] - M - logf(L));
}

// ---------------- masked per-step mean -> scalar loss ----------------
__global__ void k_loss(const int* __restrict__ target,
                       const float* __restrict__ nll,
                       float* __restrict__ out) {
  __shared__ float red[SS];
  int s = threadIdx.x; // 512
  float sl = 0.f, cnt = 0.f;
#pragma unroll
  for (int b = 0; b < NB; ++b) {
    int idx = b * SS + s;
    if (target[idx] != 0) { sl += nll[idx]; cnt += 1.f; }
  }
  red[s] = sl / fmaxf(cnt, 1.f);
  __syncthreads();
  for (int st = 256; st > 0; st >>= 1) {
    if (s < st) red[s] += red[s + st];
    __syncthreads();
  }
  if (s == 0) out[0] = red[0] / (float)SS;
}

// ---------------- launch ----------------
extern "C" void kernel_launch(void* const* d_in, const int* in_sizes, int n_in,
                              void* d_out, int out_size, void* d_ws, size_t ws_size,
                              hipStream_t stream) {
  (void)in_sizes; (void)n_in; (void)out_size; (void)ws_size;
  const int*   text   = (const int*)d_in[0];
  const int*   target = (const int*)d_in[1];
  const float* embed  = (const float*)d_in[2];
  const float* W1     = (const float*)d_in[3];
  const float* b1     = (const float*)d_in[4];
  const float* W2     = (const float*)d_in[5];
  const float* b2     = (const float*)d_in[6];
  const float* Wo     = (const float*)d_in[7];
  const float* bo     = (const float*)d_in[8];
  float* out = (float*)d_out;
  char* ws = (char*)d_ws;

  const size_t SZ_E = (size_t)MTOK * KDIM * 2; // 16.78 MB
  unsigned short* E   = (unsigned short*)(ws);
  unsigned short* H1  = (unsigned short*)(ws + SZ_E);
  unsigned short* H2  = (unsigned short*)(ws + 2 * SZ_E);
  unsigned short* W1t = (unsigned short*)(ws + 3 * SZ_E);
  unsigned short* W2t = (unsigned short*)(ws + 3 * SZ_E + (size_t)HID * HID * 2);
  unsigned short* Wot = (unsigned short*)(ws + 3 * SZ_E + (size_t)2 * HID * HID * 2);
  char* after = ws + 3 * SZ_E + (size_t)2 * HID * HID * 2 + (size_t)VOCAB * HID * 2;
  float* tlog = (float*)after;
  float* nll  = (float*)(after + (size_t)MTOK * 4);
  float* pmax = (float*)E;   // E dead after GEMM1
  float* psum = (float*)H1;  // H1 dead after GEMM2

  k_transpose_bf16<<<dim3(HID / 32, HID / 32), 256, 0, stream>>>(W1, W1t, HID, HID);
  k_transpose_bf16<<<dim3(HID / 32, HID / 32), 256, 0, stream>>>(W2, W2t, HID, HID);
  k_transpose_bf16<<<dim3(VOCAB / 32, HID / 32), 256, 0, stream>>>(Wo, Wot, HID, VOCAB);
  k_gather_e<<<MTOK, 256, 0, stream>>>(text, embed, E);

  k_gemm_ffn<<<dim3(HID / 128, MTOK / 128), 256, 0, stream>>>(E, W1t, b1, H1, HID);
  k_gemm_ffn<<<dim3(HID / 128, MTOK / 128), 256, 0, stream>>>(H1, W2t, b2, H2, HID);

  k_gemm_vocab<<<dim3((MTOK / 256) * (VOCAB / 256)), 512, 0, stream>>>(
      H2, Wot, bo, pmax, psum, tlog, target);

  k_reduce_nll<<<MTOK, 64, 0, stream>>>(pmax, psum, tlog, nll);
  k_loss<<<1, SS, 0, stream>>>(target, nll, out);
}